// Round 6
// baseline (216.940 us; speedup 1.0000x reference)
//
#include <hip/hip_runtime.h>
#include <hip/hip_bf16.h>
#include <math.h>

#define N 1024
#define F 128
#define NEG_SLOPE 0.01f

typedef float f32x4 __attribute__((ext_vector_type(4)));

// Kernel 1: Vp = V @ W^T + b ; s_i = Vp @ a_i ; s_j = Vp @ a_j
__global__ __launch_bounds__(128) void gat_prep(
    const float* __restrict__ V,     // N*F
    const float* __restrict__ W,     // F*F
    const float* __restrict__ b,     // F
    const float* __restrict__ a,     // 3F: [a_i | a_j | a_t]
    float* __restrict__ Vp,          // N*F
    float* __restrict__ s_i,         // N
    float* __restrict__ s_j)         // N
{
    const int i = blockIdx.x;
    const int f = threadIdx.x;        // 0..127
    __shared__ float vsh[F];
    vsh[f] = V[i * F + f];
    __syncthreads();

    const float* wrow = W + f * F;
    float acc = b[f];
#pragma unroll 4
    for (int k = 0; k < F; ++k) acc += vsh[k] * wrow[k];
    Vp[(size_t)i * F + f] = acc;

    float pi = acc * a[f];
    float pj = acc * a[F + f];
#pragma unroll
    for (int off = 32; off; off >>= 1) {
        pi += __shfl_xor(pi, off, 64);
        pj += __shfl_xor(pj, off, 64);
    }
    __shared__ float r[4];
    if ((f & 63) == 0) { r[(f >> 6) * 2 + 0] = pi; r[(f >> 6) * 2 + 1] = pj; }
    __syncthreads();
    if (f == 0) { s_i[i] = r[0] + r[2]; s_j[i] = r[1] + r[3]; }
}

// Kernel 2: one block (512 thr, 8 waves) per ROW PAIR (A=2b, B=2b+1).
// Pipeline: P1(A) read-only -> SM(A) -> MIXED {read te(B) || write H(A)}
//           -> SM(B) -> P3(B) write-only.
// The mixed loop sustains a 1:1 read/write stream (copy-kernel-like mix).
__global__ __launch_bounds__(512, 8) void gat_main(
    const float* __restrict__ time_enc, // N*N*F
    const float* __restrict__ E,        // N*N
    const float* __restrict__ Vp,       // N*F
    const float* __restrict__ s_i,      // N
    const float* __restrict__ s_j,      // N
    const float* __restrict__ a_t,      // F
    float* __restrict__ H)              // N*N*F
{
    const int iA   = 2 * blockIdx.x;
    const int iB   = iA + 1;
    const int tid  = threadIdx.x;
    const int wave = tid >> 6;   // 0..7
    const int lane = tid & 63;
    const int half = lane >> 5;  // which row of the j-pair
    const int hl   = lane & 31;  // feature-chunk index within half

    __shared__ float scA[N], scB[N];   // scores -> exp
    __shared__ float sjs[N];           // staged s_j
    __shared__ float EshA[N], EshB[N]; // staged E rows
    __shared__ float red[16];

    for (int j = tid; j < N; j += 512) {
        sjs[j]  = s_j[j];
        EshA[j] = E[(size_t)iA * N + j];
        EshB[j] = E[(size_t)iB * N + j];
    }

    const f32x4 at4 = *reinterpret_cast<const f32x4*>(a_t + 4 * hl);
    const float siA = s_i[iA];
    const float siB = s_i[iB];
    const float* teA = time_enc + (size_t)iA * N * F;
    const float* teB = time_enc + (size_t)iB * N * F;
    float* HrowA = H + (size_t)iA * N * F;
    float* HrowB = H + (size_t)iB * N * F;
    __syncthreads();

    // ---- P1(A): scores + leaky_relu + per-wave max (read-only) ----
    float lmax = -INFINITY;
    for (int jb = wave * 4; jb < N; jb += 32) {
        const f32x4 t0 = __builtin_nontemporal_load(
            reinterpret_cast<const f32x4*>(teA + (size_t)(jb + half) * F + 4 * hl));
        const f32x4 t1 = __builtin_nontemporal_load(
            reinterpret_cast<const f32x4*>(teA + (size_t)(jb + 2 + half) * F + 4 * hl));
        float d0 = t0.x * at4.x + t0.y * at4.y + t0.z * at4.z + t0.w * at4.w;
        float d1 = t1.x * at4.x + t1.y * at4.y + t1.z * at4.z + t1.w * at4.w;
#pragma unroll
        for (int off = 16; off; off >>= 1) {
            d0 += __shfl_xor(d0, off, 64);
            d1 += __shfl_xor(d1, off, 64);
        }
        if (hl == 0) {   // lanes 0 and 32 hold full row sums
            float s0 = siA + sjs[jb + half] + d0;
            float s1 = siA + sjs[jb + 2 + half] + d1;
            s0 = (s0 > 0.f) ? s0 : NEG_SLOPE * s0;
            s1 = (s1 > 0.f) ? s1 : NEG_SLOPE * s1;
            scA[jb + half] = s0;
            scA[jb + 2 + half] = s1;
            lmax = fmaxf(lmax, fmaxf(s0, s1));
        }
    }
    lmax = fmaxf(lmax, __shfl_xor(lmax, 32, 64));
    if (lane == 0) red[wave] = lmax;
    __syncthreads();
    float mA = red[0];
#pragma unroll
    for (int w = 1; w < 8; ++w) mA = fmaxf(mA, red[w]);

    // ---- SM(A): exp + sum ----
    float lsum = 0.f;
    for (int j = tid; j < N; j += 512) {
        float e = __expf(scA[j] - mA);
        scA[j] = e;
        lsum += e;
    }
#pragma unroll
    for (int off = 32; off; off >>= 1) lsum += __shfl_xor(lsum, off, 64);
    if (lane == 0) red[8 + wave] = lsum;
    __syncthreads();
    float totA = red[8];
#pragma unroll
    for (int w = 1; w < 8; ++w) totA += red[8 + w];
    const float invA = 1.f / totA;

    // ---- MIXED: read te(B) + compute scB  ||  write H(A) ----
    float lmaxB = -INFINITY;
    for (int jb = wave * 4; jb < N; jb += 32) {
        const f32x4 t0 = __builtin_nontemporal_load(
            reinterpret_cast<const f32x4*>(teB + (size_t)(jb + half) * F + 4 * hl));
        const f32x4 t1 = __builtin_nontemporal_load(
            reinterpret_cast<const f32x4*>(teB + (size_t)(jb + 2 + half) * F + 4 * hl));
        const f32x4 v0 = *reinterpret_cast<const f32x4*>(Vp + (size_t)(jb + half) * F + 4 * hl);
        const f32x4 v1 = *reinterpret_cast<const f32x4*>(Vp + (size_t)(jb + 2 + half) * F + 4 * hl);

        const float kA0 = scA[jb + half] * invA * EshA[jb + half];
        const float kA1 = scA[jb + 2 + half] * invA * EshA[jb + 2 + half];
        *reinterpret_cast<f32x4*>(HrowA + (size_t)(jb + half) * F + 4 * hl) = v0 * kA0;
        *reinterpret_cast<f32x4*>(HrowA + (size_t)(jb + 2 + half) * F + 4 * hl) = v1 * kA1;

        float d0 = t0.x * at4.x + t0.y * at4.y + t0.z * at4.z + t0.w * at4.w;
        float d1 = t1.x * at4.x + t1.y * at4.y + t1.z * at4.z + t1.w * at4.w;
#pragma unroll
        for (int off = 16; off; off >>= 1) {
            d0 += __shfl_xor(d0, off, 64);
            d1 += __shfl_xor(d1, off, 64);
        }
        if (hl == 0) {
            float s0 = siB + sjs[jb + half] + d0;
            float s1 = siB + sjs[jb + 2 + half] + d1;
            s0 = (s0 > 0.f) ? s0 : NEG_SLOPE * s0;
            s1 = (s1 > 0.f) ? s1 : NEG_SLOPE * s1;
            scB[jb + half] = s0;
            scB[jb + 2 + half] = s1;
            lmaxB = fmaxf(lmaxB, fmaxf(s0, s1));
        }
    }
    lmaxB = fmaxf(lmaxB, __shfl_xor(lmaxB, 32, 64));
    if (lane == 0) red[wave] = lmaxB;   // red[0..7] safe: mA reads all done pre-SM(A) barrier
    __syncthreads();
    float mB = red[0];
#pragma unroll
    for (int w = 1; w < 8; ++w) mB = fmaxf(mB, red[w]);

    // ---- SM(B): exp + sum ----
    float lsumB = 0.f;
    for (int j = tid; j < N; j += 512) {
        float e = __expf(scB[j] - mB);
        scB[j] = e;
        lsumB += e;
    }
#pragma unroll
    for (int off = 32; off; off >>= 1) lsumB += __shfl_xor(lsumB, off, 64);
    if (lane == 0) red[8 + wave] = lsumB;  // safe: invA reads done before mixed loop, all waves past barrier
    __syncthreads();
    float totB = red[8];
#pragma unroll
    for (int w = 1; w < 8; ++w) totB += red[8 + w];
    const float invB = 1.f / totB;

    // ---- P3(B): write H(B) (write-only) ----
    for (int jb = wave * 4; jb < N; jb += 32) {
        const f32x4 v0 = *reinterpret_cast<const f32x4*>(Vp + (size_t)(jb + half) * F + 4 * hl);
        const f32x4 v1 = *reinterpret_cast<const f32x4*>(Vp + (size_t)(jb + 2 + half) * F + 4 * hl);
        const float kB0 = scB[jb + half] * invB * EshB[jb + half];
        const float kB1 = scB[jb + 2 + half] * invB * EshB[jb + 2 + half];
        *reinterpret_cast<f32x4*>(HrowB + (size_t)(jb + half) * F + 4 * hl) = v0 * kB0;
        *reinterpret_cast<f32x4*>(HrowB + (size_t)(jb + 2 + half) * F + 4 * hl) = v1 * kB1;
    }
}

extern "C" void kernel_launch(void* const* d_in, const int* in_sizes, int n_in,
                              void* d_out, int out_size, void* d_ws, size_t ws_size,
                              hipStream_t stream) {
    const float* V  = (const float*)d_in[0];  // N*F
    const float* E  = (const float*)d_in[1];  // N*N
    const float* TE = (const float*)d_in[2];  // N*N*F
    const float* W  = (const float*)d_in[3];  // F*F
    const float* Wb = (const float*)d_in[4];  // F
    const float* a  = (const float*)d_in[5];  // 3F

    float* H = (float*)d_out;

    float* Vp  = (float*)d_ws;
    float* s_i = Vp + (size_t)N * F;
    float* s_j = s_i + N;

    gat_prep<<<N, 128, 0, stream>>>(V, W, Wb, a, Vp, s_i, s_j);
    gat_main<<<N / 2, 512, 0, stream>>>(TE, E, Vp, s_i, s_j, a + 2 * F, H);
}

// Round 7
// 196.007 us; speedup vs baseline: 1.1068x; 1.1068x over previous
//
#include <hip/hip_runtime.h>
#include <hip/hip_bf16.h>
#include <math.h>

#define N 1024
#define F 128
#define NEG_SLOPE 0.01f

typedef float f32x4 __attribute__((ext_vector_type(4)));

// Kernel 1: Vp = V @ W^T + b ; s_i = Vp @ a_i ; s_j = Vp @ a_j
__global__ __launch_bounds__(128) void gat_prep(
    const float* __restrict__ V,     // N*F
    const float* __restrict__ W,     // F*F
    const float* __restrict__ b,     // F
    const float* __restrict__ a,     // 3F: [a_i | a_j | a_t]
    float* __restrict__ Vp,          // N*F
    float* __restrict__ s_i,         // N
    float* __restrict__ s_j)         // N
{
    const int i = blockIdx.x;
    const int f = threadIdx.x;        // 0..127
    __shared__ float vsh[F];
    vsh[f] = V[i * F + f];
    __syncthreads();

    const float* wrow = W + f * F;
    float acc = b[f];
#pragma unroll 4
    for (int k = 0; k < F; ++k) acc += vsh[k] * wrow[k];
    Vp[(size_t)i * F + f] = acc;

    float pi = acc * a[f];
    float pj = acc * a[F + f];
#pragma unroll
    for (int off = 32; off; off >>= 1) {
        pi += __shfl_xor(pi, off, 64);
        pj += __shfl_xor(pj, off, 64);
    }
    __shared__ float r[4];
    if ((f & 63) == 0) { r[(f >> 6) * 2 + 0] = pi; r[(f >> 6) * 2 + 1] = pj; }
    __syncthreads();
    if (f == 0) { s_i[i] = r[0] + r[2]; s_j[i] = r[1] + r[3]; }
}

// Kernel 2a (PURE READ): scores -> softmax -> kscale[i,j] = att[i,j]*E[i,j]
__global__ __launch_bounds__(512, 8) void gat_score(
    const float* __restrict__ time_enc, // N*N*F
    const float* __restrict__ E,        // N*N
    const float* __restrict__ s_i,      // N
    const float* __restrict__ s_j,      // N
    const float* __restrict__ a_t,      // F
    float* __restrict__ kscale)         // N*N
{
    const int i    = blockIdx.x;
    const int tid  = threadIdx.x;
    const int wave = tid >> 6;   // 0..7
    const int lane = tid & 63;
    const int half = lane >> 5;  // which row of the pair
    const int hl   = lane & 31;  // feature-chunk index within half

    __shared__ float sc[N];      // scores -> exp
    __shared__ float sjs[N];     // staged s_j
    __shared__ float Esh[N];     // staged E row
    __shared__ float red[16];

    const float* Erow = E + (size_t)i * N;
    for (int j = tid; j < N; j += 512) { sjs[j] = s_j[j]; Esh[j] = Erow[j]; }

    const f32x4 at4 = *reinterpret_cast<const f32x4*>(a_t + 4 * hl);
    const float si  = s_i[i];
    const float* te_row = time_enc + (size_t)i * N * F;
    __syncthreads();

    // scores + leaky_relu + per-wave max (x2 unroll = 4 rows/iter)
    float lmax = -INFINITY;
    for (int jb = wave * 4; jb < N; jb += 32) {
        const f32x4 t0 = __builtin_nontemporal_load(
            reinterpret_cast<const f32x4*>(te_row + (size_t)(jb + half) * F + 4 * hl));
        const f32x4 t1 = __builtin_nontemporal_load(
            reinterpret_cast<const f32x4*>(te_row + (size_t)(jb + 2 + half) * F + 4 * hl));
        float d0 = t0.x * at4.x + t0.y * at4.y + t0.z * at4.z + t0.w * at4.w;
        float d1 = t1.x * at4.x + t1.y * at4.y + t1.z * at4.z + t1.w * at4.w;
#pragma unroll
        for (int off = 16; off; off >>= 1) {
            d0 += __shfl_xor(d0, off, 64);
            d1 += __shfl_xor(d1, off, 64);
        }
        if (hl == 0) {   // lanes 0 and 32 hold full row sums
            float s0 = si + sjs[jb + half] + d0;
            float s1 = si + sjs[jb + 2 + half] + d1;
            s0 = (s0 > 0.f) ? s0 : NEG_SLOPE * s0;
            s1 = (s1 > 0.f) ? s1 : NEG_SLOPE * s1;
            sc[jb + half] = s0;
            sc[jb + 2 + half] = s1;
            lmax = fmaxf(lmax, fmaxf(s0, s1));
        }
    }
    lmax = fmaxf(lmax, __shfl_xor(lmax, 32, 64));
    if (lane == 0) red[wave] = lmax;
    __syncthreads();
    float m = red[0];
#pragma unroll
    for (int w = 1; w < 8; ++w) m = fmaxf(m, red[w]);

    // exp + sum
    float lsum = 0.f;
    for (int j = tid; j < N; j += 512) {
        float e = __expf(sc[j] - m);
        sc[j] = e;
        lsum += e;
    }
#pragma unroll
    for (int off = 32; off; off >>= 1) lsum += __shfl_xor(lsum, off, 64);
    if (lane == 0) red[8 + wave] = lsum;
    __syncthreads();
    float tot = red[8];
#pragma unroll
    for (int w = 1; w < 8; ++w) tot += red[8 + w];
    const float inv = 1.f / tot;

    // emit fused per-edge scale (4 KB per row)
    float* krow = kscale + (size_t)i * N;
    for (int j = tid; j < N; j += 512) krow[j] = sc[j] * inv * Esh[j];
}

// Kernel 2b (PURE WRITE): H[i,j,:] = kscale[i,j] * Vp[j,:]
__global__ __launch_bounds__(512, 8) void gat_h(
    const float* __restrict__ kscale,   // N*N
    const float* __restrict__ Vp,       // N*F (L2/L3-hot)
    float* __restrict__ H)              // N*N*F
{
    const int i    = blockIdx.x;
    const int tid  = threadIdx.x;
    const int wave = tid >> 6;
    const int lane = tid & 63;
    const int half = lane >> 5;
    const int hl   = lane & 31;

    __shared__ float kk[N];
    const float* krow = kscale + (size_t)i * N;
    for (int j = tid; j < N; j += 512) kk[j] = krow[j];
    __syncthreads();

    float* Hrow = H + (size_t)i * N * F;
    for (int jb = wave * 4; jb < N; jb += 32) {
        const f32x4 v0 = *reinterpret_cast<const f32x4*>(Vp + (size_t)(jb + half) * F + 4 * hl);
        const f32x4 v1 = *reinterpret_cast<const f32x4*>(Vp + (size_t)(jb + 2 + half) * F + 4 * hl);
        const float k0 = kk[jb + half];
        const float k1 = kk[jb + 2 + half];
        __builtin_nontemporal_store(v0 * k0,
            reinterpret_cast<f32x4*>(Hrow + (size_t)(jb + half) * F + 4 * hl));
        __builtin_nontemporal_store(v1 * k1,
            reinterpret_cast<f32x4*>(Hrow + (size_t)(jb + 2 + half) * F + 4 * hl));
    }
}

extern "C" void kernel_launch(void* const* d_in, const int* in_sizes, int n_in,
                              void* d_out, int out_size, void* d_ws, size_t ws_size,
                              hipStream_t stream) {
    const float* V  = (const float*)d_in[0];  // N*F
    const float* E  = (const float*)d_in[1];  // N*N
    const float* TE = (const float*)d_in[2];  // N*N*F
    const float* W  = (const float*)d_in[3];  // F*F
    const float* Wb = (const float*)d_in[4];  // F
    const float* a  = (const float*)d_in[5];  // 3F

    float* H = (float*)d_out;

    // ws layout: Vp (N*F), s_i (N), s_j (N), kscale (N*N)  ~= 4.6 MB
    float* Vp     = (float*)d_ws;
    float* s_i    = Vp + (size_t)N * F;
    float* s_j    = s_i + N;
    float* kscale = s_j + N;

    gat_prep<<<N, 128, 0, stream>>>(V, W, Wb, a, Vp, s_i, s_j);
    gat_score<<<N, 512, 0, stream>>>(TE, E, s_i, s_j, a + 2 * F, kscale);
    gat_h<<<N, 512, 0, stream>>>(kscale, Vp, H);
}